// Round 17
// baseline (517.073 us; speedup 1.0000x reference)
//
#include <hip/hip_runtime.h>
#include <math.h>

#define Bn 2
#define Nn 16384
#define En 262144
#define Kn 256
#define Cn 128
#define Rn 512
#define Ln 4
#define LDP 72      // padded LDS row (u16) for a 64-wide k chunk
#define NSPLIT 64   // k-splits for forward transform
#define MMSPLIT 4   // i-splits for mode mix
#define MMB (Cn*MMSPLIT)   // 512 mm blocks in fused k_mmgrad

typedef float f32x4 __attribute__((ext_vector_type(4)));
typedef short s16x8 __attribute__((ext_vector_type(8)));

__device__ __forceinline__ float gelu_f(float x){
  return 0.5f*x*(1.0f + erff(x*0.70710678118654752440f));
}
__device__ __forceinline__ unsigned short f2b(float x){
  unsigned int u = __float_as_uint(x);
  unsigned int r = (u + 0x7FFFu + ((u>>16)&1u)) >> 16;
  return (unsigned short)r;
}
__device__ __forceinline__ float b2f(unsigned short h){
  return __uint_as_float(((unsigned int)h)<<16);
}
__device__ __forceinline__ unsigned int pack2(float lo, float hi){
  return (unsigned int)f2b(lo) | ((unsigned int)f2b(hi) << 16);
}

// ---------------- small prep kernels ----------------

__global__ __launch_bounds__(256) void k_nw(const float* __restrict__ nwt,
                                            const float* __restrict__ msk,
                                            float* __restrict__ nw){
  int i = blockIdx.x*256 + threadIdx.x;
  nw[i] = nwt[i]*msk[i];
}

// basis[n][r] bf16 (r<256: cos, r>=256: sin) and basisT[b*512+r][n_local] bf16
__global__ __launch_bounds__(256) void k_basis(const float* __restrict__ nodes,
                                               const float* __restrict__ modes,
                                               const float* __restrict__ spl,
                                               unsigned short* __restrict__ basis,
                                               unsigned short* __restrict__ basisT){
  __shared__ unsigned short tile[32*520];
  int gn0 = blockIdx.x*32;
  int tid = threadIdx.x;             // k = tid
  float m0 = modes[tid*3+0]*spl[0];
  float m1 = modes[tid*3+1]*spl[1];
  float m2 = modes[tid*3+2]*spl[2];
  for (int j=0;j<32;j++){
    const float* nd = nodes + (size_t)(gn0+j)*3;
    float t = nd[0]*m0 + nd[1]*m1 + nd[2]*m2;
    float s,c;
    sincosf(t,&s,&c);
    tile[j*520 + tid]       = f2b(c);
    tile[j*520 + 256 + tid] = f2b(s);
  }
  __syncthreads();
  // n-major rows
  int row = tid>>3, col0 = (tid&7)*64;
  #pragma unroll
  for (int q=0;q<8;q++){
    s16x8 v = *(const s16x8*)&tile[row*520 + col0 + q*8];
    *(s16x8*)(basis + (size_t)(gn0+row)*Rn + col0 + q*8) = v;
  }
  // transposed rows (per batch)
  int b = gn0 >> 14;
  int nl = gn0 & (Nn-1);
  #pragma unroll
  for (int h=0; h<2; h++){
    int r = h*256 + tid;             // tile column index == r
    unsigned short* dst = basisT + ((size_t)(b*Rn + r))*Nn + nl;
    #pragma unroll
    for (int q=0;q<4;q++){
      unsigned short tmp[8];
      #pragma unroll
      for (int e=0;e<8;e++) tmp[e] = tile[(q*8+e)*520 + r];
      *(s16x8*)(dst + q*8) = *(const s16x8*)tmp;
    }
  }
}

// lift: h = x @ fc0_w^T + b ; writes hpack[n][0:128] and hwT[c][n]
__global__ __launch_bounds__(256) void k_lift(const float* __restrict__ x,
                                              const float* __restrict__ w,
                                              const float* __restrict__ bias,
                                              const float* __restrict__ nw,
                                              unsigned short* __restrict__ hpack,
                                              unsigned short* __restrict__ hwT){
  __shared__ float ht[64*132];
  int gn0 = blockIdx.x*64;
  int tid = threadIdx.x;
  int c = tid & 127, rh = tid >> 7;
  float w0 = w[c*3], w1 = w[c*3+1], w2 = w[c*3+2], bb = bias[c];
  for (int j=0;j<32;j++){
    int n = rh*32 + j;
    const float* xp = x + (size_t)(gn0+n)*3;
    float v = bb + xp[0]*w0 + xp[1]*w1 + xp[2]*w2;
    ht[n*132 + c] = v;
    hpack[(size_t)(gn0+n)*Cn + c] = f2b(v);
  }
  __syncthreads();
  int b = gn0 >> 14, nl = gn0 & (Nn-1);
  int cc = tid>>1, hf = tid&1;
  unsigned short* dst = hwT + ((size_t)(b*Cn + cc))*Nn + nl + hf*32;
  #pragma unroll
  for (int q=0;q<8;q++){
    int n = hf*32 + q*4;
    float4 nv = *(const float4*)&nw[(size_t)b*Nn + nl + n];
    ushort4 pk;
    pk.x = f2b(ht[(n+0)*132+cc]*nv.x);
    pk.y = f2b(ht[(n+1)*132+cc]*nv.y);
    pk.z = f2b(ht[(n+2)*132+cc]*nv.z);
    pk.w = f2b(ht[(n+3)*132+cc]*nv.w);
    *(ushort4*)(dst + q*4) = pk;
  }
}

// combined weights bf16: W2[l*128+o][0:128]=ws_w.
// Gradient cols permuted to dim-major: W2[o][128 + d*128 + c] = gws_w[o][c*3+d]
__global__ __launch_bounds__(128) void k_w2c(const float* __restrict__ ws_w,
                                             const float* __restrict__ ws_b,
                                             const float* __restrict__ gws_w,
                                             const float* __restrict__ gws_b,
                                             unsigned short* __restrict__ W2,
                                             float* __restrict__ bias2){
  int bid = blockIdx.x;
  int tid = threadIdx.x;      // channel c
  unsigned short* wrow = W2 + (size_t)bid*Rn;
  wrow[tid] = f2b(ws_w[(size_t)bid*Cn + tid]);
  const float* g = gws_w + (size_t)bid*384;
  wrow[128+tid] = f2b(g[tid*3+0]);
  wrow[256+tid] = f2b(g[tid*3+1]);
  wrow[384+tid] = f2b(g[tid*3+2]);
  if (tid==0) bias2[bid] = ws_b[bid] + gws_b[bid];
}

__global__ __launch_bounds__(256) void k_cvt(const float* __restrict__ in,
                                             unsigned short* __restrict__ out, int n){
  int i = blockIdx.x*256 + threadIdx.x;
  if (i < n) out[i] = f2b(in[i]);
}

// ---------------- CSR build ----------------

__global__ __launch_bounds__(256) void k_count(const int* __restrict__ de,
                                               int* __restrict__ cnt){
  int i = blockIdx.x*256 + threadIdx.x;
  int b = i >> 18;
  int tgt = de[(size_t)i*2];
  atomicAdd(&cnt[b*Nn + tgt], 1);
}

__global__ __launch_bounds__(1024) void k_scan(const int* __restrict__ cnt,
                                               int* __restrict__ rowptr,
                                               int* __restrict__ cursor){
  __shared__ int part[1024];
  int t = threadIdx.x;
  int b = t >> 9;
  int li = t & 511;
  int loc[32];
  int s = 0;
  int base = b*Nn + li*32;
  #pragma unroll
  for (int j=0;j<32;j++){ loc[j] = s; s += cnt[base+j]; }
  part[t] = s;
  __syncthreads();
  int run = s;
  for (int off=1; off<512; off<<=1){
    int v = (li >= off) ? part[t-off] : 0;
    __syncthreads();
    part[t] += v;
    __syncthreads();
  }
  int incl = part[t];
  int excl = incl - run;
  int rbase = b*(Nn+1) + li*32;
  #pragma unroll
  for (int j=0;j<32;j++){
    int val = excl + loc[j];
    rowptr[rbase+j] = val;
    cursor[base+j]  = val;
  }
  if (li == 511) rowptr[b*(Nn+1) + Nn] = incl;
}

__global__ __launch_bounds__(256) void k_fill(const int* __restrict__ de,
                                              const float* __restrict__ egw,
                                              int* __restrict__ cursor,
                                              float4* __restrict__ epack){
  int i = blockIdx.x*256 + threadIdx.x;
  int b = i >> 18;
  int tgt = de[(size_t)i*2];
  int src = de[(size_t)i*2+1];
  int pos = atomicAdd(&cursor[b*Nn + tgt], 1);
  const float* g = egw + (size_t)i*3;
  float4 pk;
  pk.x = __int_as_float(src);
  pk.y = g[0]; pk.z = g[1]; pk.w = g[2];
  epack[(size_t)b*En + pos] = pk;
}

// ---------------- shared MFMA staging/cores ----------------
__device__ __forceinline__ void stage_tile(const unsigned short* __restrict__ g, size_t ldg,
                                           unsigned short* __restrict__ lds, int tid){
  int row = tid >> 3;          // 0..31
  int seg = (tid & 7) * 8;     // 0..56
  #pragma unroll
  for (int rb=0; rb<4; rb++){
    s16x8 v = *(const s16x8*)(g + (size_t)(row + rb*32)*ldg + seg);
    *(s16x8*)(lds + (size_t)(row + rb*32)*LDP + seg) = v;
  }
}
__device__ __forceinline__ void stage_tile512(const unsigned short* __restrict__ g, size_t ldg,
                                              unsigned short* __restrict__ lds, int tid){
  int row = tid >> 3;          // 0..63
  int seg = (tid & 7) * 8;
  #pragma unroll
  for (int rb=0; rb<2; rb++){
    s16x8 v = *(const s16x8*)(g + (size_t)(row + rb*64)*ldg + seg);
    *(s16x8*)(lds + (size_t)(row + rb*64)*LDP + seg) = v;
  }
}

// 128x128 core, 4 waves as 2x2, acc[4][4]
__device__ __forceinline__ void mfma_chunk(const unsigned short* __restrict__ As,
                                           const unsigned short* __restrict__ Bs,
                                           f32x4 acc[4][4], int wm, int wn, int lr, int lg){
  #pragma unroll
  for (int kk=0; kk<2; kk++){
    s16x8 a[4], b[4];
    #pragma unroll
    for (int i=0;i<4;i++)
      a[i] = *(const s16x8*)(As + (size_t)(wm*64 + i*16 + lr)*LDP + kk*32 + lg*8);
    #pragma unroll
    for (int i=0;i<4;i++)
      b[i] = *(const s16x8*)(Bs + (size_t)(wn*64 + i*16 + lr)*LDP + kk*32 + lg*8);
    #pragma unroll
    for (int i=0;i<4;i++)
      #pragma unroll
      for (int j=0;j<4;j++)
        acc[i][j] = __builtin_amdgcn_mfma_f32_16x16x32_bf16(a[i], b[j], acc[i][j], 0, 0, 0);
  }
}

// 128x128 core, 8 waves as 2x4, acc[4][2]
__device__ __forceinline__ void mfma_chunk8(const unsigned short* __restrict__ As,
                                            const unsigned short* __restrict__ Bs,
                                            f32x4 acc[4][2], int wm, int wn, int lr, int lg){
  #pragma unroll
  for (int kk=0; kk<2; kk++){
    s16x8 a[4], b[2];
    #pragma unroll
    for (int i=0;i<4;i++)
      a[i] = *(const s16x8*)(As + (size_t)(wm*64 + i*16 + lr)*LDP + kk*32 + lg*8);
    #pragma unroll
    for (int j=0;j<2;j++)
      b[j] = *(const s16x8*)(Bs + (size_t)(wn*32 + j*16 + lr)*LDP + kk*32 + lg*8);
    #pragma unroll
    for (int i=0;i<4;i++)
      #pragma unroll
      for (int j=0;j<2;j++)
        acc[i][j] = __builtin_amdgcn_mfma_f32_16x16x32_bf16(a[i], b[j], acc[i][j], 0, 0, 0);
  }
}

// forward transform partials (bf16): part16[ks][b][c][r]
__global__ __launch_bounds__(256) void k_fwd_mfma(const unsigned short* __restrict__ basisT,
                                                  const unsigned short* __restrict__ hwT,
                                                  unsigned short* __restrict__ part16){
  __shared__ unsigned short As[128*LDP];
  __shared__ unsigned short Bs[128*LDP];
  int tid = threadIdx.x;
  int mt = blockIdx.x;   // 4 r-tiles
  int ks = blockIdx.y;   // NSPLIT k-splits
  int b  = blockIdx.z;
  const int KSP = Nn/NSPLIT;   // 256
  const unsigned short* A  = basisT + ((size_t)(b*Rn + mt*128))*Nn + (size_t)ks*KSP;
  const unsigned short* Bp = hwT   + ((size_t)(b*Cn))*Nn + (size_t)ks*KSP;
  f32x4 acc[4][4] = {};
  int l = tid & 63, w = tid >> 6, wm = w >> 1, wn = w & 1, lr = l & 15, lg = l >> 4;
  for (int k0 = 0; k0 < KSP; k0 += 64){
    stage_tile(A + k0, Nn, As, tid);
    stage_tile(Bp + k0, Nn, Bs, tid);
    __syncthreads();
    mfma_chunk(As, Bs, acc, wm, wn, lr, lg);
    __syncthreads();
  }
  unsigned short* pb = part16 + ((size_t)ks*Bn + b)*(Cn*Rn);
  int r0 = mt*128 + wm*64;
  int c0 = wn*64;
  #pragma unroll
  for (int i=0;i<4;i++)
    #pragma unroll
    for (int j=0;j<4;j++){
      int r = r0 + i*16 + lg*4;
      int c = c0 + j*16 + lr;
      unsigned short* p = pb + (size_t)c*Rn + r;
      *(unsigned int*)(p)     = pack2(acc[i][j][0], acc[i][j][1]);
      *(unsigned int*)(p + 2) = pack2(acc[i][j][2], acc[i][j][3]);
    }
}

// reduce bf16 partials: xf[b][c][r] = sum_ks part16[ks][...]
__global__ __launch_bounds__(256) void k_reduce(const unsigned int* __restrict__ part32,
                                                float* __restrict__ xf){
  int idx = blockIdx.x*256 + threadIdx.x;   // 0..Bn*Cn*Rn/2-1
  const int STRIDE = Bn*Cn*Rn/2;            // u32 elements per split
  float s0 = 0.f, s1 = 0.f;
  #pragma unroll 8
  for (int ks=0; ks<NSPLIT; ks++){
    unsigned int v = part32[(size_t)ks*STRIDE + idx];
    s0 += b2f((unsigned short)(v & 0xffffu));
    s1 += b2f((unsigned short)(v >> 16));
  }
  float2 o; o.x = s0; o.y = s1;
  *(float2*)&xf[(size_t)idx*2] = o;
}

// ---------------- fused mode-mix + gradient gather ----------------
// blocks [0, MMB): mode mix (float4-vectorized, 4 i-splits x 4 wave-groups)
// blocks [MMB, MMB + B*N/2): edge gather, 2 nodes/block, 2 waves/node, 4-edge batches
__global__ __launch_bounds__(256) void k_mmgrad(const float* __restrict__ xf,
                                                const float* __restrict__ wc,
                                                const float* __restrict__ ws,
                                                float* __restrict__ Fpart,
                                                const unsigned short* __restrict__ hpack,
                                                const float4* __restrict__ epack,
                                                const int* __restrict__ rowptr,
                                                unsigned short* __restrict__ gradbuf){
  __shared__ float smem[3072];
  int bid = blockIdx.x;
  int tid = threadIdx.x;
  if (bid < MMB){
    int o  = bid & 127;
    int is = bid >> 7;
    int g = tid >> 6;          // 0..3 (8 i each)
    int l = tid & 63;
    int t4 = l*4;
    f32x4 fc0={},fs0={},fc1={},fs1={};
    #pragma unroll
    for (int ii=0; ii<8; ii++){
      int i = is*32 + g*8 + ii;
      f32x4 wc4 = *(const f32x4*)&wc[((size_t)i*Cn + o)*Kn + t4];
      f32x4 ws4 = *(const f32x4*)&ws[((size_t)i*Cn + o)*Kn + t4];
      f32x4 x0c = *(const f32x4*)&xf[(size_t)i*Rn + t4];
      f32x4 x0s = *(const f32x4*)&xf[(size_t)i*Rn + 256 + t4];
      f32x4 x1c = *(const f32x4*)&xf[(size_t)Cn*Rn + (size_t)i*Rn + t4];
      f32x4 x1s = *(const f32x4*)&xf[(size_t)Cn*Rn + (size_t)i*Rn + 256 + t4];
      fc0 += x0c*wc4 + x0s*ws4;  fs0 += x0c*ws4 - x0s*wc4;
      fc1 += x1c*wc4 + x1s*ws4;  fs1 += x1c*ws4 - x1s*wc4;
    }
    float (*red)[64][16] = (float(*)[64][16])smem;
    if (g > 0){
      float* r = red[g-1][l];
      *(f32x4*)&r[0]  = fc0;  *(f32x4*)&r[4]  = fs0;
      *(f32x4*)&r[8]  = fc1;  *(f32x4*)&r[12] = fs1;
    }
    __syncthreads();
    if (g == 0){
      #pragma unroll
      for (int q=0;q<3;q++){
        const float* r = red[q][l];
        fc0 += *(const f32x4*)&r[0];   fs0 += *(const f32x4*)&r[4];
        fc1 += *(const f32x4*)&r[8];   fs1 += *(const f32x4*)&r[12];
      }
      float* f0 = Fpart + ((size_t)(is*Bn + 0)*Cn + o)*Rn;
      float* f1 = Fpart + ((size_t)(is*Bn + 1)*Cn + o)*Rn;
      *(f32x4*)&f0[t4]       = fc0;
      *(f32x4*)&f0[256 + t4] = fs0;
      *(f32x4*)&f1[t4]       = fc1;
      *(f32x4*)&f1[256 + t4] = fs1;
    }
    return;
  }
  // ---- gradient gather ----
  int gg = bid - MMB;
  int b = gg >> 13;
  int n = ((gg & 8191) << 1) | (tid >> 7);
  int wv = (tid >> 6) & 1;
  int l  = tid & 63;
  int half = tid >> 7;
  const unsigned short* hb = hpack + (size_t)b*Nn*Cn;
  unsigned int ft2 = *(const unsigned int*)(hb + (size_t)n*Cn + 2*l);
  float ftlo = b2f((unsigned short)(ft2 & 0xffffu));
  float fthi = b2f((unsigned short)(ft2 >> 16));
  int beg = rowptr[b*(Nn+1) + n];
  int end = rowptr[b*(Nn+1) + n + 1];
  const float4* ep = epack + (size_t)b*En;
  float a0lo=0.f,a0hi=0.f,a1lo=0.f,a1hi=0.f,a2lo=0.f,a2hi=0.f;
  int j = beg + wv;
  for (; j + 6 < end; j += 8){
    float4 pk0 = ep[j];
    float4 pk1 = ep[j+2];
    float4 pk2 = ep[j+4];
    float4 pk3 = ep[j+6];
    unsigned int h0 = *(const unsigned int*)(hb + (size_t)__float_as_int(pk0.x)*Cn + 2*l);
    unsigned int h1 = *(const unsigned int*)(hb + (size_t)__float_as_int(pk1.x)*Cn + 2*l);
    unsigned int h2 = *(const unsigned int*)(hb + (size_t)__float_as_int(pk2.x)*Cn + 2*l);
    unsigned int h3 = *(const unsigned int*)(hb + (size_t)__float_as_int(pk3.x)*Cn + 2*l);
    float d0lo = b2f((unsigned short)(h0 & 0xffffu)) - ftlo;
    float d0hi = b2f((unsigned short)(h0 >> 16))     - fthi;
    float d1lo = b2f((unsigned short)(h1 & 0xffffu)) - ftlo;
    float d1hi = b2f((unsigned short)(h1 >> 16))     - fthi;
    float d2lo = b2f((unsigned short)(h2 & 0xffffu)) - ftlo;
    float d2hi = b2f((unsigned short)(h2 >> 16))     - fthi;
    float d3lo = b2f((unsigned short)(h3 & 0xffffu)) - ftlo;
    float d3hi = b2f((unsigned short)(h3 >> 16))     - fthi;
    a0lo += pk0.y*d0lo + pk1.y*d1lo + pk2.y*d2lo + pk3.y*d3lo;
    a0hi += pk0.y*d0hi + pk1.y*d1hi + pk2.y*d2hi + pk3.y*d3hi;
    a1lo += pk0.z*d0lo + pk1.z*d1lo + pk2.z*d2lo + pk3.z*d3lo;
    a1hi += pk0.z*d0hi + pk1.z*d1hi + pk2.z*d2hi + pk3.z*d3hi;
    a2lo += pk0.w*d0lo + pk1.w*d1lo + pk2.w*d2lo + pk3.w*d3lo;
    a2hi += pk0.w*d0hi + pk1.w*d1hi + pk2.w*d2hi + pk3.w*d3hi;
  }
  for (; j < end; j += 2){
    float4 pk = ep[j];
    int src = __float_as_int(pk.x);
    unsigned int hv = *(const unsigned int*)(hb + (size_t)src*Cn + 2*l);
    float dlo = b2f((unsigned short)(hv & 0xffffu)) - ftlo;
    float dhi = b2f((unsigned short)(hv >> 16))     - fthi;
    a0lo += pk.y*dlo; a0hi += pk.y*dhi;
    a1lo += pk.z*dlo; a1hi += pk.z*dhi;
    a2lo += pk.w*dlo; a2hi += pk.w*dhi;
  }
  if (wv == 1){
    float* r = &smem[(half*64 + l)*7];
    r[0]=a0lo; r[1]=a0hi; r[2]=a1lo; r[3]=a1hi; r[4]=a2lo; r[5]=a2hi;
  }
  __syncthreads();
  if (wv == 0){
    const float* r = &smem[(half*64 + l)*7];
    a0lo+=r[0]; a0hi+=r[1]; a1lo+=r[2]; a1hi+=r[3]; a2lo+=r[4]; a2hi+=r[5];
    unsigned short* o = gradbuf + ((size_t)b*Nn + n)*384;
    *(unsigned int*)(o + 2*l)       = pack2(a0lo, a0hi);
    *(unsigned int*)(o + 128 + 2*l) = pack2(a1lo, a1hi);
    *(unsigned int*)(o + 256 + 2*l) = pack2(a2lo, a2hi);
  }
}

// combine MMSPLIT i-split partials, apply +-2 scale, convert to bf16
__global__ __launch_bounds__(256) void k_fcvt(const float* __restrict__ Fpart,
                                              unsigned short* __restrict__ Fbf){
  int idx = blockIdx.x*256 + threadIdx.x;   // Bn*Cn*Rn
  float s = 0.f;
  #pragma unroll
  for (int q=0;q<MMSPLIT;q++)
    s += Fpart[(size_t)q*Bn*Cn*Rn + idx];
  float sc = ((idx & 511) < 256) ? 2.f : -2.f;
  Fbf[idx] = f2b(sc*s);
}

// inverse transform + ws/gws combined GEMM, fused epilogue
// 512 threads, 128x128 tile; A2 staged from hpack(cols 0-127) + gradbuf(cols 128-511).
template<int GELU, int WRITE_AUX>
__global__ __launch_bounds__(512) void k_invcomb(const unsigned short* __restrict__ basis,
                                                 const unsigned short* __restrict__ Fbf,
                                                 const unsigned short* __restrict__ gradbuf,
                                                 const unsigned short* __restrict__ W2l,
                                                 const float* __restrict__ bias2l,
                                                 const float* __restrict__ nw,
                                                 unsigned short* __restrict__ hpack,
                                                 unsigned short* __restrict__ hwT){
  __shared__ unsigned short As1[128*LDP];
  __shared__ unsigned short Bs1[128*LDP];
  __shared__ unsigned short As2[128*LDP];
  __shared__ unsigned short Bs2[128*LDP];
  int tid = threadIdx.x;
  int nt = blockIdx.x;   // 128 n-tiles per batch
  int b  = blockIdx.y;
  size_t nbase = (size_t)b*Nn + (size_t)nt*128;
  f32x4 acc[4][2] = {};
  int l = tid & 63, w = tid >> 6, wm = w >> 2, wn = w & 3, lr = l & 15, lg = l >> 4;
  const unsigned short* A1 = basis + nbase*Rn;
  const unsigned short* B1 = Fbf + (size_t)b*Cn*Rn;
  for (int k0=0;k0<512;k0+=64){
    stage_tile512(A1+k0, Rn, As1, tid);
    stage_tile512(B1+k0, Rn, Bs1, tid);
    if (k0 < 128) stage_tile512(hpack + nbase*Cn + k0, Cn, As2, tid);
    else          stage_tile512(gradbuf + nbase*384 + (k0-128), 384, As2, tid);
    stage_tile512(W2l+k0, Rn, Bs2, tid);
    __syncthreads();
    mfma_chunk8(As1,Bs1,acc,wm,wn,lr,lg);
    mfma_chunk8(As2,Bs2,acc,wm,wn,lr,lg);
    __syncthreads();
  }
  #pragma unroll
  for (int i=0;i<4;i++){
    int nloc = wm*64 + i*16 + lg*4;
    float4 w4;
    if (WRITE_AUX) w4 = *(const float4*)&nw[(size_t)b*Nn + nt*128 + nloc];
    #pragma unroll
    for (int j=0;j<2;j++){
      int c = wn*32 + j*16 + lr;
      float bsv = bias2l[c];
      float v[4];
      #pragma unroll
      for (int e=0;e<4;e++){
        v[e] = acc[i][j][e] + bsv;
        if (GELU) v[e] = gelu_f(v[e]);
        hpack[(nbase + nloc + e)*Cn + c] = f2b(v[e]);
      }
      if (WRITE_AUX){
        ushort4 pk;
        pk.x = f2b(v[0]*w4.x); pk.y = f2b(v[1]*w4.y);
        pk.z = f2b(v[2]*w4.z); pk.w = f2b(v[3]*w4.w);
        *(ushort4*)&hwT[((size_t)(b*Cn + c))*Nn + nt*128 + nloc] = pk;
      }
    }
  }
}

// fc1 + gelu -> h2 bf16 (512 threads, 128x128 tile)
__global__ __launch_bounds__(512) void k_fc1(const unsigned short* __restrict__ hpack,
                                             const unsigned short* __restrict__ fw,
                                             const float* __restrict__ fb,
                                             unsigned short* __restrict__ h2){
  __shared__ unsigned short As[128*LDP];
  __shared__ unsigned short Bs[128*LDP];
  int tid = threadIdx.x;
  int nt = blockIdx.x;
  int b  = blockIdx.y;
  size_t nbase = (size_t)b*Nn + (size_t)nt*128;
  f32x4 acc[4][2] = {};
  int l = tid & 63, w = tid >> 6, wm = w >> 2, wn = w & 3, lr = l & 15, lg = l >> 4;
  const unsigned short* A = hpack + nbase*Cn;
  for (int k0=0;k0<128;k0+=64){
    stage_tile512(A+k0, Cn, As, tid);
    stage_tile512(fw+k0, Cn, Bs, tid);
    __syncthreads();
    mfma_chunk8(As,Bs,acc,wm,wn,lr,lg);
    __syncthreads();
  }
  #pragma unroll
  for (int i=0;i<4;i++){
    int nloc = wm*64 + i*16 + lg*4;
    #pragma unroll
    for (int j=0;j<2;j++){
      int c = wn*32 + j*16 + lr;
      float bsv = fb[c];
      #pragma unroll
      for (int e=0;e<4;e++){
        float v = gelu_f(acc[i][j][e] + bsv);
        h2[(nbase + nloc + e)*Cn + c] = f2b(v);
      }
    }
  }
}

// final projection
__global__ __launch_bounds__(256) void k_out(const unsigned short* __restrict__ h2,
                                             const float* __restrict__ w,
                                             const float* __restrict__ bptr,
                                             float* __restrict__ outp){
  int tid = threadIdx.x;
  int node = blockIdx.x*4 + (tid>>6);
  int f = tid & 63;
  const unsigned short* hp = h2 + (size_t)node*Cn;
  float s = b2f(hp[f])*w[f] + b2f(hp[f+64])*w[f+64];
  #pragma unroll
  for (int off=32; off>0; off>>=1) s += __shfl_down(s, off);
  if (f==0) outp[node] = s + bptr[0];
}

// ---------------- workspace layout (byte offsets) ----------------
static constexpr size_t OB_BASIS  = 0;                         // 33554432
static constexpr size_t OB_BASIST = OB_BASIS  + 33554432;      // 33554432
static constexpr size_t OB_GRAD   = OB_BASIST + 33554432;      // 25165824 (B*N*384 u16)
static constexpr size_t OB_HWT    = OB_GRAD   + 25165824;      // 8388608
static constexpr size_t OB_H2     = OB_HWT    + 8388608;       // 8388608
static constexpr size_t OB_HP     = OB_H2     + 8388608;       // 8388608
static constexpr size_t OB_NW     = OB_HP     + 8388608;       // 131072
static constexpr size_t OB_XF     = OB_NW     + 131072;        // 524288
static constexpr size_t OB_FBF    = OB_XF     + 524288;        // 262144
static constexpr size_t OB_FPART  = OB_FBF    + 262144;        // 2097152 (MMSPLIT=4)
static constexpr size_t OB_W2     = OB_FPART  + 2097152;       // 524288
static constexpr size_t OB_B2     = OB_W2     + 524288;        // 2048
static constexpr size_t OB_FC1W   = OB_B2     + 2048;          // 32768
static constexpr size_t OB_EPACK  = OB_FC1W   + 32768;         // 8388608
static constexpr size_t OB_INT    = OB_EPACK  + 8388608;       // 524288
static constexpr size_t OB_PART   = OB_INT    + 524288;        // 16777216 (bf16, NSPLIT=64)

extern "C" void kernel_launch(void* const* d_in, const int* in_sizes, int n_in,
                              void* d_out, int out_size, void* d_ws, size_t ws_size,
                              hipStream_t stream) {
  const float* x            = (const float*)d_in[0];
  const float* nodes        = (const float*)d_in[1];
  const float* node_mask    = (const float*)d_in[2];
  const float* node_weights = (const float*)d_in[3];
  const int*   de           = (const int*)  d_in[4];
  const float* egw          = (const float*)d_in[5];
  const float* modes        = (const float*)d_in[6];
  const float* spl          = (const float*)d_in[7];
  const float* wc           = (const float*)d_in[8];
  const float* wsp          = (const float*)d_in[9];
  // d_in[10] = weights_0 : unused (b0 == 0)
  const float* fc0_w        = (const float*)d_in[11];
  const float* fc0_b        = (const float*)d_in[12];
  const float* ws_w         = (const float*)d_in[13];
  const float* ws_b         = (const float*)d_in[14];
  const float* gws_w        = (const float*)d_in[15];
  const float* gws_b        = (const float*)d_in[16];
  const float* fc1_w        = (const float*)d_in[17];
  const float* fc1_b        = (const float*)d_in[18];
  const float* fc2_w        = (const float*)d_in[19];
  const float* fc2_b        = (const float*)d_in[20];
  float* outp = (float*)d_out;

  char* wsb = (char*)d_ws;
  unsigned short* basis   = (unsigned short*)(wsb + OB_BASIS);
  unsigned short* basisT  = (unsigned short*)(wsb + OB_BASIST);
  unsigned short* gradbuf = (unsigned short*)(wsb + OB_GRAD);
  unsigned short* hwT     = (unsigned short*)(wsb + OB_HWT);
  unsigned short* h2      = (unsigned short*)(wsb + OB_H2);
  unsigned short* hpack   = (unsigned short*)(wsb + OB_HP);
  float* nw               = (float*)(wsb + OB_NW);
  float* xf               = (float*)(wsb + OB_XF);
  unsigned short* Fbf     = (unsigned short*)(wsb + OB_FBF);
  float* Fpart            = (float*)(wsb + OB_FPART);
  unsigned short* W2      = (unsigned short*)(wsb + OB_W2);
  float* bias2            = (float*)(wsb + OB_B2);
  unsigned short* fc1wb   = (unsigned short*)(wsb + OB_FC1W);
  float4* epack           = (float4*)(wsb + OB_EPACK);
  int* count  = (int*)(wsb + OB_INT);
  int* rowptr = count + Bn*Nn;
  int* cursor = rowptr + Bn*(Nn+1);
  unsigned short* part16 = (unsigned short*)(wsb + OB_PART);

  // prep
  k_nw<<<(Bn*Nn)/256, 256, 0, stream>>>(node_weights, node_mask, nw);
  k_basis<<<(Bn*Nn)/32, 256, 0, stream>>>(nodes, modes, spl, basis, basisT);
  k_lift<<<(Bn*Nn)/64, 256, 0, stream>>>(x, fc0_w, fc0_b, nw, hpack, hwT);

  // CSR build
  (void)hipMemsetAsync(count, 0, (size_t)Bn*Nn*sizeof(int), stream);
  k_count<<<(Bn*En)/256, 256, 0, stream>>>(de, count);
  k_scan<<<1, 1024, 0, stream>>>(count, rowptr, cursor);
  k_fill<<<(Bn*En)/256, 256, 0, stream>>>(de, egw, cursor, epack);

  // weights
  k_w2c<<<Ln*Cn, 128, 0, stream>>>(ws_w, ws_b, gws_w, gws_b, W2, bias2);
  k_cvt<<<64, 256, 0, stream>>>(fc1_w, fc1wb, Cn*Cn);

  for (int l=0; l<Ln; l++){
    k_fwd_mfma<<<dim3(4,NSPLIT,2), 256, 0, stream>>>(basisT, hwT, part16);
    k_reduce<<<(Bn*Cn*Rn/2)/256, 256, 0, stream>>>((const unsigned int*)part16, xf);
    k_mmgrad<<<MMB + (Bn*Nn)/2, 256, 0, stream>>>(xf, wc + (size_t)l*Cn*Cn*Kn,
                                                  wsp + (size_t)l*Cn*Cn*Kn, Fpart,
                                                  hpack, epack, rowptr, gradbuf);
    k_fcvt<<<(Bn*Cn*Rn)/256, 256, 0, stream>>>(Fpart, Fbf);
    if (l < Ln-1){
      k_invcomb<1,1><<<dim3(Nn/128,2), 512, 0, stream>>>(
          basis, Fbf, gradbuf, W2 + (size_t)l*Cn*Rn, bias2 + l*Cn, nw, hpack, hwT);
    } else {
      k_invcomb<0,0><<<dim3(Nn/128,2), 512, 0, stream>>>(
          basis, Fbf, gradbuf, W2 + (size_t)l*Cn*Rn, bias2 + l*Cn, nw, hpack, hwT);
    }
  }

  k_fc1<<<dim3(Nn/128,2), 512, 0, stream>>>(hpack, fc1wb, fc1_b, h2);
  k_out<<<(Bn*Nn)/4, 256, 0, stream>>>(h2, fc2_w, fc2_b, outp);
}

// Round 18
// 507.341 us; speedup vs baseline: 1.0192x; 1.0192x over previous
//
#include <hip/hip_runtime.h>
#include <math.h>

#define Bn 2
#define Nn 16384
#define En 262144
#define Kn 256
#define Cn 128
#define Rn 512
#define Ln 4
#define LDP 72      // padded LDS row (u16) for a 64-wide k chunk
#define NSPLIT 64   // k-splits for forward transform
#define MMSPLIT 4   // i-splits for mode mix

typedef float f32x4 __attribute__((ext_vector_type(4)));
typedef short s16x8 __attribute__((ext_vector_type(8)));

__device__ __forceinline__ float gelu_f(float x){
  return 0.5f*x*(1.0f + erff(x*0.70710678118654752440f));
}
__device__ __forceinline__ unsigned short f2b(float x){
  unsigned int u = __float_as_uint(x);
  unsigned int r = (u + 0x7FFFu + ((u>>16)&1u)) >> 16;
  return (unsigned short)r;
}
__device__ __forceinline__ float b2f(unsigned short h){
  return __uint_as_float(((unsigned int)h)<<16);
}
__device__ __forceinline__ unsigned int pack2(float lo, float hi){
  return (unsigned int)f2b(lo) | ((unsigned int)f2b(hi) << 16);
}

// ---------------- small prep kernels ----------------

__global__ __launch_bounds__(256) void k_nw(const float* __restrict__ nwt,
                                            const float* __restrict__ msk,
                                            float* __restrict__ nw){
  int i = blockIdx.x*256 + threadIdx.x;
  nw[i] = nwt[i]*msk[i];
}

// basis[n][r] bf16 (r<256: cos, r>=256: sin) and basisT[b*512+r][n_local] bf16
__global__ __launch_bounds__(256) void k_basis(const float* __restrict__ nodes,
                                               const float* __restrict__ modes,
                                               const float* __restrict__ spl,
                                               unsigned short* __restrict__ basis,
                                               unsigned short* __restrict__ basisT){
  __shared__ unsigned short tile[32*520];
  int gn0 = blockIdx.x*32;
  int tid = threadIdx.x;             // k = tid
  float m0 = modes[tid*3+0]*spl[0];
  float m1 = modes[tid*3+1]*spl[1];
  float m2 = modes[tid*3+2]*spl[2];
  for (int j=0;j<32;j++){
    const float* nd = nodes + (size_t)(gn0+j)*3;
    float t = nd[0]*m0 + nd[1]*m1 + nd[2]*m2;
    float s,c;
    sincosf(t,&s,&c);
    tile[j*520 + tid]       = f2b(c);
    tile[j*520 + 256 + tid] = f2b(s);
  }
  __syncthreads();
  // n-major rows
  int row = tid>>3, col0 = (tid&7)*64;
  #pragma unroll
  for (int q=0;q<8;q++){
    s16x8 v = *(const s16x8*)&tile[row*520 + col0 + q*8];
    *(s16x8*)(basis + (size_t)(gn0+row)*Rn + col0 + q*8) = v;
  }
  // transposed rows (per batch)
  int b = gn0 >> 14;
  int nl = gn0 & (Nn-1);
  #pragma unroll
  for (int h=0; h<2; h++){
    int r = h*256 + tid;             // tile column index == r
    unsigned short* dst = basisT + ((size_t)(b*Rn + r))*Nn + nl;
    #pragma unroll
    for (int q=0;q<4;q++){
      unsigned short tmp[8];
      #pragma unroll
      for (int e=0;e<8;e++) tmp[e] = tile[(q*8+e)*520 + r];
      *(s16x8*)(dst + q*8) = *(const s16x8*)tmp;
    }
  }
}

// lift: h = x @ fc0_w^T + b ; writes hpack[n][0:128] and hwT[c][n]
__global__ __launch_bounds__(256) void k_lift(const float* __restrict__ x,
                                              const float* __restrict__ w,
                                              const float* __restrict__ bias,
                                              const float* __restrict__ nw,
                                              unsigned short* __restrict__ hpack,
                                              unsigned short* __restrict__ hwT){
  __shared__ float ht[64*132];
  int gn0 = blockIdx.x*64;
  int tid = threadIdx.x;
  int c = tid & 127, rh = tid >> 7;
  float w0 = w[c*3], w1 = w[c*3+1], w2 = w[c*3+2], bb = bias[c];
  for (int j=0;j<32;j++){
    int n = rh*32 + j;
    const float* xp = x + (size_t)(gn0+n)*3;
    float v = bb + xp[0]*w0 + xp[1]*w1 + xp[2]*w2;
    ht[n*132 + c] = v;
    hpack[(size_t)(gn0+n)*Cn + c] = f2b(v);
  }
  __syncthreads();
  int b = gn0 >> 14, nl = gn0 & (Nn-1);
  int cc = tid>>1, hf = tid&1;
  unsigned short* dst = hwT + ((size_t)(b*Cn + cc))*Nn + nl + hf*32;
  #pragma unroll
  for (int q=0;q<8;q++){
    int n = hf*32 + q*4;
    float4 nv = *(const float4*)&nw[(size_t)b*Nn + nl + n];
    ushort4 pk;
    pk.x = f2b(ht[(n+0)*132+cc]*nv.x);
    pk.y = f2b(ht[(n+1)*132+cc]*nv.y);
    pk.z = f2b(ht[(n+2)*132+cc]*nv.z);
    pk.w = f2b(ht[(n+3)*132+cc]*nv.w);
    *(ushort4*)(dst + q*4) = pk;
  }
}

// combined weights bf16: W2[l*128+o][0:128]=ws_w.
// Gradient cols permuted to dim-major: W2[o][128 + d*128 + c] = gws_w[o][c*3+d]
__global__ __launch_bounds__(128) void k_w2c(const float* __restrict__ ws_w,
                                             const float* __restrict__ ws_b,
                                             const float* __restrict__ gws_w,
                                             const float* __restrict__ gws_b,
                                             unsigned short* __restrict__ W2,
                                             float* __restrict__ bias2){
  int bid = blockIdx.x;
  int tid = threadIdx.x;      // channel c
  unsigned short* wrow = W2 + (size_t)bid*Rn;
  wrow[tid] = f2b(ws_w[(size_t)bid*Cn + tid]);
  const float* g = gws_w + (size_t)bid*384;
  wrow[128+tid] = f2b(g[tid*3+0]);
  wrow[256+tid] = f2b(g[tid*3+1]);
  wrow[384+tid] = f2b(g[tid*3+2]);
  if (tid==0) bias2[bid] = ws_b[bid] + gws_b[bid];
}

__global__ __launch_bounds__(256) void k_cvt(const float* __restrict__ in,
                                             unsigned short* __restrict__ out, int n){
  int i = blockIdx.x*256 + threadIdx.x;
  if (i < n) out[i] = f2b(in[i]);
}

// ---------------- CSR build ----------------

__global__ __launch_bounds__(256) void k_count(const int* __restrict__ de,
                                               int* __restrict__ cnt){
  int i = blockIdx.x*256 + threadIdx.x;
  int b = i >> 18;
  int tgt = de[(size_t)i*2];
  atomicAdd(&cnt[b*Nn + tgt], 1);
}

__global__ __launch_bounds__(1024) void k_scan(const int* __restrict__ cnt,
                                               int* __restrict__ rowptr,
                                               int* __restrict__ cursor){
  __shared__ int part[1024];
  int t = threadIdx.x;
  int b = t >> 9;
  int li = t & 511;
  int loc[32];
  int s = 0;
  int base = b*Nn + li*32;
  #pragma unroll
  for (int j=0;j<32;j++){ loc[j] = s; s += cnt[base+j]; }
  part[t] = s;
  __syncthreads();
  int run = s;
  for (int off=1; off<512; off<<=1){
    int v = (li >= off) ? part[t-off] : 0;
    __syncthreads();
    part[t] += v;
    __syncthreads();
  }
  int incl = part[t];
  int excl = incl - run;
  int rbase = b*(Nn+1) + li*32;
  #pragma unroll
  for (int j=0;j<32;j++){
    int val = excl + loc[j];
    rowptr[rbase+j] = val;
    cursor[base+j]  = val;
  }
  if (li == 511) rowptr[b*(Nn+1) + Nn] = incl;
}

__global__ __launch_bounds__(256) void k_fill(const int* __restrict__ de,
                                              const float* __restrict__ egw,
                                              int* __restrict__ cursor,
                                              float4* __restrict__ epack){
  int i = blockIdx.x*256 + threadIdx.x;
  int b = i >> 18;
  int tgt = de[(size_t)i*2];
  int src = de[(size_t)i*2+1];
  int pos = atomicAdd(&cursor[b*Nn + tgt], 1);
  const float* g = egw + (size_t)i*3;
  float4 pk;
  pk.x = __int_as_float(src);
  pk.y = g[0]; pk.z = g[1]; pk.w = g[2];
  epack[(size_t)b*En + pos] = pk;
}

// ---------------- gradient gather: 2 waves/node, 4-edge batches ----------------
__global__ __launch_bounds__(128) void k_grad(const unsigned short* __restrict__ hpack,
                                              const float4* __restrict__ epack,
                                              const int* __restrict__ rowptr,
                                              unsigned short* __restrict__ gradbuf){
  int bid = blockIdx.x;
  int b = bid >> 14, n = bid & (Nn-1);
  int tid = threadIdx.x;
  int wv = tid >> 6;     // 0,1
  int l  = tid & 63;     // lane: channels 2l, 2l+1
  const unsigned short* hb = hpack + (size_t)b*Nn*Cn;
  unsigned int ft2 = *(const unsigned int*)(hb + (size_t)n*Cn + 2*l);
  float ftlo = b2f((unsigned short)(ft2 & 0xffffu));
  float fthi = b2f((unsigned short)(ft2 >> 16));
  int beg = rowptr[b*(Nn+1) + n];
  int end = rowptr[b*(Nn+1) + n + 1];
  const float4* ep = epack + (size_t)b*En;
  float a0lo=0.f,a0hi=0.f,a1lo=0.f,a1hi=0.f,a2lo=0.f,a2hi=0.f;
  int j = beg + wv;
  for (; j + 6 < end; j += 8){
    float4 pk0 = ep[j];
    float4 pk1 = ep[j+2];
    float4 pk2 = ep[j+4];
    float4 pk3 = ep[j+6];
    unsigned int h0 = *(const unsigned int*)(hb + (size_t)__float_as_int(pk0.x)*Cn + 2*l);
    unsigned int h1 = *(const unsigned int*)(hb + (size_t)__float_as_int(pk1.x)*Cn + 2*l);
    unsigned int h2 = *(const unsigned int*)(hb + (size_t)__float_as_int(pk2.x)*Cn + 2*l);
    unsigned int h3 = *(const unsigned int*)(hb + (size_t)__float_as_int(pk3.x)*Cn + 2*l);
    float d0lo = b2f((unsigned short)(h0 & 0xffffu)) - ftlo;
    float d0hi = b2f((unsigned short)(h0 >> 16))     - fthi;
    float d1lo = b2f((unsigned short)(h1 & 0xffffu)) - ftlo;
    float d1hi = b2f((unsigned short)(h1 >> 16))     - fthi;
    float d2lo = b2f((unsigned short)(h2 & 0xffffu)) - ftlo;
    float d2hi = b2f((unsigned short)(h2 >> 16))     - fthi;
    float d3lo = b2f((unsigned short)(h3 & 0xffffu)) - ftlo;
    float d3hi = b2f((unsigned short)(h3 >> 16))     - fthi;
    a0lo += pk0.y*d0lo + pk1.y*d1lo + pk2.y*d2lo + pk3.y*d3lo;
    a0hi += pk0.y*d0hi + pk1.y*d1hi + pk2.y*d2hi + pk3.y*d3hi;
    a1lo += pk0.z*d0lo + pk1.z*d1lo + pk2.z*d2lo + pk3.z*d3lo;
    a1hi += pk0.z*d0hi + pk1.z*d1hi + pk2.z*d2hi + pk3.z*d3hi;
    a2lo += pk0.w*d0lo + pk1.w*d1lo + pk2.w*d2lo + pk3.w*d3lo;
    a2hi += pk0.w*d0hi + pk1.w*d1hi + pk2.w*d2hi + pk3.w*d3hi;
  }
  for (; j < end; j += 2){
    float4 pk = ep[j];
    int src = __float_as_int(pk.x);
    unsigned int hv = *(const unsigned int*)(hb + (size_t)src*Cn + 2*l);
    float dlo = b2f((unsigned short)(hv & 0xffffu)) - ftlo;
    float dhi = b2f((unsigned short)(hv >> 16))     - fthi;
    a0lo += pk.y*dlo; a0hi += pk.y*dhi;
    a1lo += pk.z*dlo; a1hi += pk.z*dhi;
    a2lo += pk.w*dlo; a2hi += pk.w*dhi;
  }
  __shared__ float red[64*7];
  if (wv == 1){
    float* r = &red[l*7];
    r[0]=a0lo; r[1]=a0hi; r[2]=a1lo; r[3]=a1hi; r[4]=a2lo; r[5]=a2hi;
  }
  __syncthreads();
  if (wv == 0){
    const float* r = &red[l*7];
    a0lo+=r[0]; a0hi+=r[1]; a1lo+=r[2]; a1hi+=r[3]; a2lo+=r[4]; a2hi+=r[5];
    unsigned short* o = gradbuf + ((size_t)b*Nn + n)*384;
    *(unsigned int*)(o + 2*l)       = pack2(a0lo, a0hi);
    *(unsigned int*)(o + 128 + 2*l) = pack2(a1lo, a1hi);
    *(unsigned int*)(o + 256 + 2*l) = pack2(a2lo, a2hi);
  }
}

// ---------------- shared MFMA staging/cores ----------------
__device__ __forceinline__ void stage_tile(const unsigned short* __restrict__ g, size_t ldg,
                                           unsigned short* __restrict__ lds, int tid){
  int row = tid >> 3;          // 0..31
  int seg = (tid & 7) * 8;     // 0..56
  #pragma unroll
  for (int rb=0; rb<4; rb++){
    s16x8 v = *(const s16x8*)(g + (size_t)(row + rb*32)*ldg + seg);
    *(s16x8*)(lds + (size_t)(row + rb*32)*LDP + seg) = v;
  }
}
__device__ __forceinline__ void stage_tile512(const unsigned short* __restrict__ g, size_t ldg,
                                              unsigned short* __restrict__ lds, int tid){
  int row = tid >> 3;          // 0..63
  int seg = (tid & 7) * 8;
  #pragma unroll
  for (int rb=0; rb<2; rb++){
    s16x8 v = *(const s16x8*)(g + (size_t)(row + rb*64)*ldg + seg);
    *(s16x8*)(lds + (size_t)(row + rb*64)*LDP + seg) = v;
  }
}

// 128x128 core, 4 waves as 2x2, acc[4][4]
__device__ __forceinline__ void mfma_chunk(const unsigned short* __restrict__ As,
                                           const unsigned short* __restrict__ Bs,
                                           f32x4 acc[4][4], int wm, int wn, int lr, int lg){
  #pragma unroll
  for (int kk=0; kk<2; kk++){
    s16x8 a[4], b[4];
    #pragma unroll
    for (int i=0;i<4;i++)
      a[i] = *(const s16x8*)(As + (size_t)(wm*64 + i*16 + lr)*LDP + kk*32 + lg*8);
    #pragma unroll
    for (int i=0;i<4;i++)
      b[i] = *(const s16x8*)(Bs + (size_t)(wn*64 + i*16 + lr)*LDP + kk*32 + lg*8);
    #pragma unroll
    for (int i=0;i<4;i++)
      #pragma unroll
      for (int j=0;j<4;j++)
        acc[i][j] = __builtin_amdgcn_mfma_f32_16x16x32_bf16(a[i], b[j], acc[i][j], 0, 0, 0);
  }
}

// 128x128 core, 8 waves as 2x4, acc[4][2]
__device__ __forceinline__ void mfma_chunk8(const unsigned short* __restrict__ As,
                                            const unsigned short* __restrict__ Bs,
                                            f32x4 acc[4][2], int wm, int wn, int lr, int lg){
  #pragma unroll
  for (int kk=0; kk<2; kk++){
    s16x8 a[4], b[2];
    #pragma unroll
    for (int i=0;i<4;i++)
      a[i] = *(const s16x8*)(As + (size_t)(wm*64 + i*16 + lr)*LDP + kk*32 + lg*8);
    #pragma unroll
    for (int j=0;j<2;j++)
      b[j] = *(const s16x8*)(Bs + (size_t)(wn*32 + j*16 + lr)*LDP + kk*32 + lg*8);
    #pragma unroll
    for (int i=0;i<4;i++)
      #pragma unroll
      for (int j=0;j<2;j++)
        acc[i][j] = __builtin_amdgcn_mfma_f32_16x16x32_bf16(a[i], b[j], acc[i][j], 0, 0, 0);
  }
}

// forward transform partials (bf16): part16[ks][b][c][r]
__global__ __launch_bounds__(256) void k_fwd_mfma(const unsigned short* __restrict__ basisT,
                                                  const unsigned short* __restrict__ hwT,
                                                  unsigned short* __restrict__ part16){
  __shared__ unsigned short As[128*LDP];
  __shared__ unsigned short Bs[128*LDP];
  int tid = threadIdx.x;
  int mt = blockIdx.x;   // 4 r-tiles
  int ks = blockIdx.y;   // NSPLIT k-splits
  int b  = blockIdx.z;
  const int KSP = Nn/NSPLIT;   // 256
  const unsigned short* A  = basisT + ((size_t)(b*Rn + mt*128))*Nn + (size_t)ks*KSP;
  const unsigned short* Bp = hwT   + ((size_t)(b*Cn))*Nn + (size_t)ks*KSP;
  f32x4 acc[4][4] = {};
  int l = tid & 63, w = tid >> 6, wm = w >> 1, wn = w & 1, lr = l & 15, lg = l >> 4;
  for (int k0 = 0; k0 < KSP; k0 += 64){
    stage_tile(A + k0, Nn, As, tid);
    stage_tile(Bp + k0, Nn, Bs, tid);
    __syncthreads();
    mfma_chunk(As, Bs, acc, wm, wn, lr, lg);
    __syncthreads();
  }
  unsigned short* pb = part16 + ((size_t)ks*Bn + b)*(Cn*Rn);
  int r0 = mt*128 + wm*64;
  int c0 = wn*64;
  #pragma unroll
  for (int i=0;i<4;i++)
    #pragma unroll
    for (int j=0;j<4;j++){
      int r = r0 + i*16 + lg*4;
      int c = c0 + j*16 + lr;
      unsigned short* p = pb + (size_t)c*Rn + r;
      *(unsigned int*)(p)     = pack2(acc[i][j][0], acc[i][j][1]);
      *(unsigned int*)(p + 2) = pack2(acc[i][j][2], acc[i][j][3]);
    }
}

// reduce bf16 partials: xf[b][c][r] = sum_ks part16[ks][...]
__global__ __launch_bounds__(256) void k_reduce(const unsigned int* __restrict__ part32,
                                                float* __restrict__ xf){
  int idx = blockIdx.x*256 + threadIdx.x;   // 0..Bn*Cn*Rn/2-1
  const int STRIDE = Bn*Cn*Rn/2;            // u32 elements per split
  float s0 = 0.f, s1 = 0.f;
  #pragma unroll 8
  for (int ks=0; ks<NSPLIT; ks++){
    unsigned int v = part32[(size_t)ks*STRIDE + idx];
    s0 += b2f((unsigned short)(v & 0xffffu));
    s1 += b2f((unsigned short)(v >> 16));
  }
  float2 o; o.x = s0; o.y = s1;
  *(float2*)&xf[(size_t)idx*2] = o;
}

// mode mix (f32), float4-vectorized over k; 4 i-splits x 4 wave-groups of 8 i.
__global__ __launch_bounds__(256) void k_mm(const float* __restrict__ xf,
                                            const float* __restrict__ wc,
                                            const float* __restrict__ ws,
                                            float* __restrict__ Fpart){
  int o  = blockIdx.x;
  int is = blockIdx.y;       // 0..3
  int tid = threadIdx.x;
  int g = tid >> 6;          // 0..3 (8 i each)
  int l = tid & 63;
  int t4 = l*4;
  f32x4 fc0={},fs0={},fc1={},fs1={};
  #pragma unroll
  for (int ii=0; ii<8; ii++){
    int i = is*32 + g*8 + ii;
    f32x4 wc4 = *(const f32x4*)&wc[((size_t)i*Cn + o)*Kn + t4];
    f32x4 ws4 = *(const f32x4*)&ws[((size_t)i*Cn + o)*Kn + t4];
    f32x4 x0c = *(const f32x4*)&xf[(size_t)i*Rn + t4];
    f32x4 x0s = *(const f32x4*)&xf[(size_t)i*Rn + 256 + t4];
    f32x4 x1c = *(const f32x4*)&xf[(size_t)Cn*Rn + (size_t)i*Rn + t4];
    f32x4 x1s = *(const f32x4*)&xf[(size_t)Cn*Rn + (size_t)i*Rn + 256 + t4];
    fc0 += x0c*wc4 + x0s*ws4;  fs0 += x0c*ws4 - x0s*wc4;
    fc1 += x1c*wc4 + x1s*ws4;  fs1 += x1c*ws4 - x1s*wc4;
  }
  __shared__ float red[3][64][16];
  if (g > 0){
    float* r = red[g-1][l];
    *(f32x4*)&r[0]  = fc0;  *(f32x4*)&r[4]  = fs0;
    *(f32x4*)&r[8]  = fc1;  *(f32x4*)&r[12] = fs1;
  }
  __syncthreads();
  if (g == 0){
    #pragma unroll
    for (int q=0;q<3;q++){
      const float* r = red[q][l];
      fc0 += *(const f32x4*)&r[0];   fs0 += *(const f32x4*)&r[4];
      fc1 += *(const f32x4*)&r[8];   fs1 += *(const f32x4*)&r[12];
    }
    float* f0 = Fpart + ((size_t)(is*Bn + 0)*Cn + o)*Rn;
    float* f1 = Fpart + ((size_t)(is*Bn + 1)*Cn + o)*Rn;
    *(f32x4*)&f0[t4]       = fc0;
    *(f32x4*)&f0[256 + t4] = fs0;
    *(f32x4*)&f1[t4]       = fc1;
    *(f32x4*)&f1[256 + t4] = fs1;
  }
}

// combine MMSPLIT i-split partials, apply +-2 scale, convert to bf16
__global__ __launch_bounds__(256) void k_fcvt(const float* __restrict__ Fpart,
                                              unsigned short* __restrict__ Fbf){
  int idx = blockIdx.x*256 + threadIdx.x;   // Bn*Cn*Rn
  float s = 0.f;
  #pragma unroll
  for (int q=0;q<MMSPLIT;q++)
    s += Fpart[(size_t)q*Bn*Cn*Rn + idx];
  float sc = ((idx & 511) < 256) ? 2.f : -2.f;
  Fbf[idx] = f2b(sc*s);
}

// inverse transform + ws/gws combined GEMM, fused epilogue
// 512 threads, 128x128 tile; A2 staged from hpack(cols 0-127) + gradbuf(cols 128-511).
template<int GELU, int WRITE_AUX>
__global__ __launch_bounds__(512) void k_invcomb(const unsigned short* __restrict__ basis,
                                                 const unsigned short* __restrict__ Fbf,
                                                 const unsigned short* __restrict__ gradbuf,
                                                 const unsigned short* __restrict__ W2l,
                                                 const float* __restrict__ bias2l,
                                                 const float* __restrict__ nw,
                                                 unsigned short* __restrict__ hpack,
                                                 unsigned short* __restrict__ hwT){
  __shared__ unsigned short As1[128*LDP];
  __shared__ unsigned short Bs1[128*LDP];
  __shared__ unsigned short As2[128*LDP];
  __shared__ unsigned short Bs2[128*LDP];
  int tid = threadIdx.x;
  int nt = blockIdx.x;   // 128 n-tiles per batch
  int b  = blockIdx.y;
  size_t nbase = (size_t)b*Nn + (size_t)nt*128;
  f32x4 acc[4][2] = {};
  int l = tid & 63, w = tid >> 6, wm = w >> 2, wn = w & 3, lr = l & 15, lg = l >> 4;
  const unsigned short* A1 = basis + nbase*Rn;
  const unsigned short* B1 = Fbf + (size_t)b*Cn*Rn;
  for (int k0=0;k0<512;k0+=64){
    stage_tile512(A1+k0, Rn, As1, tid);
    stage_tile512(B1+k0, Rn, Bs1, tid);
    if (k0 < 128) stage_tile512(hpack + nbase*Cn + k0, Cn, As2, tid);
    else          stage_tile512(gradbuf + nbase*384 + (k0-128), 384, As2, tid);
    stage_tile512(W2l+k0, Rn, Bs2, tid);
    __syncthreads();
    mfma_chunk8(As1,Bs1,acc,wm,wn,lr,lg);
    mfma_chunk8(As2,Bs2,acc,wm,wn,lr,lg);
    __syncthreads();
  }
  #pragma unroll
  for (int i=0;i<4;i++){
    int nloc = wm*64 + i*16 + lg*4;
    float4 w4;
    if (WRITE_AUX) w4 = *(const float4*)&nw[(size_t)b*Nn + nt*128 + nloc];
    #pragma unroll
    for (int j=0;j<2;j++){
      int c = wn*32 + j*16 + lr;
      float bsv = bias2l[c];
      float v[4];
      #pragma unroll
      for (int e=0;e<4;e++){
        v[e] = acc[i][j][e] + bsv;
        if (GELU) v[e] = gelu_f(v[e]);
        hpack[(nbase + nloc + e)*Cn + c] = f2b(v[e]);
      }
      if (WRITE_AUX){
        ushort4 pk;
        pk.x = f2b(v[0]*w4.x); pk.y = f2b(v[1]*w4.y);
        pk.z = f2b(v[2]*w4.z); pk.w = f2b(v[3]*w4.w);
        *(ushort4*)&hwT[((size_t)(b*Cn + c))*Nn + nt*128 + nloc] = pk;
      }
    }
  }
}

// fc1 + gelu -> h2 bf16 (512 threads, 128x128 tile)
__global__ __launch_bounds__(512) void k_fc1(const unsigned short* __restrict__ hpack,
                                             const unsigned short* __restrict__ fw,
                                             const float* __restrict__ fb,
                                             unsigned short* __restrict__ h2){
  __shared__ unsigned short As[128*LDP];
  __shared__ unsigned short Bs[128*LDP];
  int tid = threadIdx.x;
  int nt = blockIdx.x;
  int b  = blockIdx.y;
  size_t nbase = (size_t)b*Nn + (size_t)nt*128;
  f32x4 acc[4][2] = {};
  int l = tid & 63, w = tid >> 6, wm = w >> 2, wn = w & 3, lr = l & 15, lg = l >> 4;
  const unsigned short* A = hpack + nbase*Cn;
  for (int k0=0;k0<128;k0+=64){
    stage_tile512(A+k0, Cn, As, tid);
    stage_tile512(fw+k0, Cn, Bs, tid);
    __syncthreads();
    mfma_chunk8(As,Bs,acc,wm,wn,lr,lg);
    __syncthreads();
  }
  #pragma unroll
  for (int i=0;i<4;i++){
    int nloc = wm*64 + i*16 + lg*4;
    #pragma unroll
    for (int j=0;j<2;j++){
      int c = wn*32 + j*16 + lr;
      float bsv = fb[c];
      #pragma unroll
      for (int e=0;e<4;e++){
        float v = gelu_f(acc[i][j][e] + bsv);
        h2[(nbase + nloc + e)*Cn + c] = f2b(v);
      }
    }
  }
}

// final projection
__global__ __launch_bounds__(256) void k_out(const unsigned short* __restrict__ h2,
                                             const float* __restrict__ w,
                                             const float* __restrict__ bptr,
                                             float* __restrict__ outp){
  int tid = threadIdx.x;
  int node = blockIdx.x*4 + (tid>>6);
  int f = tid & 63;
  const unsigned short* hp = h2 + (size_t)node*Cn;
  float s = b2f(hp[f])*w[f] + b2f(hp[f+64])*w[f+64];
  #pragma unroll
  for (int off=32; off>0; off>>=1) s += __shfl_down(s, off);
  if (f==0) outp[node] = s + bptr[0];
}

// ---------------- workspace layout (byte offsets) ----------------
static constexpr size_t OB_BASIS  = 0;                         // 33554432
static constexpr size_t OB_BASIST = OB_BASIS  + 33554432;      // 33554432
static constexpr size_t OB_GRAD   = OB_BASIST + 33554432;      // 25165824 (B*N*384 u16)
static constexpr size_t OB_HWT    = OB_GRAD   + 25165824;      // 8388608
static constexpr size_t OB_H2     = OB_HWT    + 8388608;       // 8388608
static constexpr size_t OB_HP     = OB_H2     + 8388608;       // 8388608
static constexpr size_t OB_NW     = OB_HP     + 8388608;       // 131072
static constexpr size_t OB_XF     = OB_NW     + 131072;        // 524288
static constexpr size_t OB_FBF    = OB_XF     + 524288;        // 262144
static constexpr size_t OB_FPART  = OB_FBF    + 262144;        // 2097152 (MMSPLIT=4)
static constexpr size_t OB_W2     = OB_FPART  + 2097152;       // 524288
static constexpr size_t OB_B2     = OB_W2     + 524288;        // 2048
static constexpr size_t OB_FC1W   = OB_B2     + 2048;          // 32768
static constexpr size_t OB_EPACK  = OB_FC1W   + 32768;         // 8388608
static constexpr size_t OB_INT    = OB_EPACK  + 8388608;       // 524288
static constexpr size_t OB_PART   = OB_INT    + 524288;        // 16777216 (bf16, NSPLIT=64)

extern "C" void kernel_launch(void* const* d_in, const int* in_sizes, int n_in,
                              void* d_out, int out_size, void* d_ws, size_t ws_size,
                              hipStream_t stream) {
  const float* x            = (const float*)d_in[0];
  const float* nodes        = (const float*)d_in[1];
  const float* node_mask    = (const float*)d_in[2];
  const float* node_weights = (const float*)d_in[3];
  const int*   de           = (const int*)  d_in[4];
  const float* egw          = (const float*)d_in[5];
  const float* modes        = (const float*)d_in[6];
  const float* spl          = (const float*)d_in[7];
  const float* wc           = (const float*)d_in[8];
  const float* wsp          = (const float*)d_in[9];
  // d_in[10] = weights_0 : unused (b0 == 0)
  const float* fc0_w        = (const float*)d_in[11];
  const float* fc0_b        = (const float*)d_in[12];
  const float* ws_w         = (const float*)d_in[13];
  const float* ws_b         = (const float*)d_in[14];
  const float* gws_w        = (const float*)d_in[15];
  const float* gws_b        = (const float*)d_in[16];
  const float* fc1_w        = (const float*)d_in[17];
  const float* fc1_b        = (const float*)d_in[18];
  const float* fc2_w        = (const float*)d_in[19];
  const float* fc2_b        = (const float*)d_in[20];
  float* outp = (float*)d_out;

  char* wsb = (char*)d_ws;
  unsigned short* basis   = (unsigned short*)(wsb + OB_BASIS);
  unsigned short* basisT  = (unsigned short*)(wsb + OB_BASIST);
  unsigned short* gradbuf = (unsigned short*)(wsb + OB_GRAD);
  unsigned short* hwT     = (unsigned short*)(wsb + OB_HWT);
  unsigned short* h2      = (unsigned short*)(wsb + OB_H2);
  unsigned short* hpack   = (unsigned short*)(wsb + OB_HP);
  float* nw               = (float*)(wsb + OB_NW);
  float* xf               = (float*)(wsb + OB_XF);
  unsigned short* Fbf     = (unsigned short*)(wsb + OB_FBF);
  float* Fpart            = (float*)(wsb + OB_FPART);
  unsigned short* W2      = (unsigned short*)(wsb + OB_W2);
  float* bias2            = (float*)(wsb + OB_B2);
  unsigned short* fc1wb   = (unsigned short*)(wsb + OB_FC1W);
  float4* epack           = (float4*)(wsb + OB_EPACK);
  int* count  = (int*)(wsb + OB_INT);
  int* rowptr = count + Bn*Nn;
  int* cursor = rowptr + Bn*(Nn+1);
  unsigned short* part16 = (unsigned short*)(wsb + OB_PART);

  // prep
  k_nw<<<(Bn*Nn)/256, 256, 0, stream>>>(node_weights, node_mask, nw);
  k_basis<<<(Bn*Nn)/32, 256, 0, stream>>>(nodes, modes, spl, basis, basisT);
  k_lift<<<(Bn*Nn)/64, 256, 0, stream>>>(x, fc0_w, fc0_b, nw, hpack, hwT);

  // CSR build
  (void)hipMemsetAsync(count, 0, (size_t)Bn*Nn*sizeof(int), stream);
  k_count<<<(Bn*En)/256, 256, 0, stream>>>(de, count);
  k_scan<<<1, 1024, 0, stream>>>(count, rowptr, cursor);
  k_fill<<<(Bn*En)/256, 256, 0, stream>>>(de, egw, cursor, epack);

  // weights
  k_w2c<<<Ln*Cn, 128, 0, stream>>>(ws_w, ws_b, gws_w, gws_b, W2, bias2);
  k_cvt<<<64, 256, 0, stream>>>(fc1_w, fc1wb, Cn*Cn);

  for (int l=0; l<Ln; l++){
    k_fwd_mfma<<<dim3(4,NSPLIT,2), 256, 0, stream>>>(basisT, hwT, part16);
    k_reduce<<<(Bn*Cn*Rn/2)/256, 256, 0, stream>>>((const unsigned int*)part16, xf);
    k_mm<<<dim3(Cn,MMSPLIT), 256, 0, stream>>>(xf, wc + (size_t)l*Cn*Cn*Kn,
                                               wsp + (size_t)l*Cn*Cn*Kn, Fpart);
    k_fcvt<<<(Bn*Cn*Rn)/256, 256, 0, stream>>>(Fpart, Fbf);
    k_grad<<<Bn*Nn, 128, 0, stream>>>(hpack, epack, rowptr, gradbuf);
    if (l < Ln-1){
      k_invcomb<1,1><<<dim3(Nn/128,2), 512, 0, stream>>>(
          basis, Fbf, gradbuf, W2 + (size_t)l*Cn*Rn, bias2 + l*Cn, nw, hpack, hwT);
    } else {
      k_invcomb<0,0><<<dim3(Nn/128,2), 512, 0, stream>>>(
          basis, Fbf, gradbuf, W2 + (size_t)l*Cn*Rn, bias2 + l*Cn, nw, hpack, hwT);
    }
  }

  k_fc1<<<dim3(Nn/128,2), 512, 0, stream>>>(hpack, fc1wb, fc1_b, h2);
  k_out<<<(Bn*Nn)/4, 256, 0, stream>>>(h2, fc2_w, fc2_b, outp);
}